// Round 5
// baseline (306.403 us; speedup 1.0000x reference)
//
#include <hip/hip_runtime.h>

#define N_NODES 10000
#define N_EDGES 160000
#define IN_DIM 128
#define HID 16
#define HEADS 50
#define OUT_DIM 10
#define N_GRAPHS 8
#define NHID (HEADS * HID) /* 800 */

// ---- bf16 helpers (self-contained, RNE) ----
static __device__ __forceinline__ unsigned short f2bf(float f) {
    union { float f; unsigned u; } v; v.f = f;
    unsigned u = v.u;
    unsigned r = (u + 0x7fffu + ((u >> 16) & 1u)) >> 16;
    return (unsigned short)r;
}
static __device__ __forceinline__ float bf2f(unsigned short s) {
    union { unsigned u; float f; } v; v.u = ((unsigned)s) << 16;
    return v.f;
}

// ---- K1: xp_t[h][n][c] = (x(10000x128) @ W(128x800)) head-major, bf16 ----
__global__ __launch_bounds__(256) void gemm_kernel(const float* __restrict__ x,
                                                   const float* __restrict__ W,
                                                   unsigned short* __restrict__ xpt) {
    __shared__ float As[64][128];  // As[k][m]
    __shared__ float Bs[64][64];   // Bs[k][n]
    const int tid = threadIdx.x;
    const int m0 = blockIdx.y * 128;
    const int n0 = blockIdx.x * 64;
    const int tx = tid & 15, ty = tid >> 4;
    float acc[8][4] = {};
    const int am = tid & 127;         // A loader: m in tile
    const int akg = (tid >> 7) * 32;  // A loader: k group base (0 or 32)
    const int bn = (tid & 15) * 4;    // B loader: n in tile
    const int bk = tid >> 4;          // B loader: k row base

    for (int kk = 0; kk < IN_DIM; kk += 64) {
        const int gm = m0 + am;
#pragma unroll
        for (int i = 0; i < 8; i++) {
            int k4 = akg + i * 4;
            float4 v = make_float4(0.f, 0.f, 0.f, 0.f);
            if (gm < N_NODES) v = *(const float4*)(x + gm * IN_DIM + kk + k4);
            As[k4 + 0][am] = v.x; As[k4 + 1][am] = v.y;
            As[k4 + 2][am] = v.z; As[k4 + 3][am] = v.w;
        }
#pragma unroll
        for (int i = 0; i < 4; i++) {
            int k = bk + i * 16;
            float4 v = make_float4(0.f, 0.f, 0.f, 0.f);
            if (n0 + bn < NHID) v = *(const float4*)(W + (kk + k) * NHID + n0 + bn);
            *(float4*)&Bs[k][bn] = v;
        }
        __syncthreads();
#pragma unroll
        for (int k = 0; k < 64; k++) {
            float4 a0 = *(const float4*)&As[k][ty * 8];
            float4 a1 = *(const float4*)&As[k][ty * 8 + 4];
            float4 b = *(const float4*)&Bs[k][tx * 4];
            float av[8] = {a0.x, a0.y, a0.z, a0.w, a1.x, a1.y, a1.z, a1.w};
            float bv[4] = {b.x, b.y, b.z, b.w};
#pragma unroll
            for (int i = 0; i < 8; i++)
#pragma unroll
                for (int j = 0; j < 4; j++) acc[i][j] += av[i] * bv[j];
        }
        __syncthreads();
    }
    const int gn = n0 + tx * 4;
    const int h = gn >> 4;   // head
    const int c0 = gn & 15;  // channel base
    if (gn < NHID) {
#pragma unroll
        for (int i = 0; i < 8; i++) {
            int gm = m0 + ty * 8 + i;
            if (gm < N_NODES) {
                ushort4 o;
                o.x = f2bf(acc[i][0]); o.y = f2bf(acc[i][1]);
                o.z = f2bf(acc[i][2]); o.w = f2bf(acc[i][3]);
                *(ushort4*)(xpt + ((h * N_NODES + gm) << 4) + c0) = o;  // 8B aligned
            }
        }
    }
}

// ---- K2: as_t[h][n] = xp_t[h][n][:] . a_src[h][:]; ad_t likewise ----
__global__ __launch_bounds__(256) void alpha_kernel(const unsigned short* __restrict__ xpt,
                                                    const float* __restrict__ a_src,
                                                    const float* __restrict__ a_dst,
                                                    float* __restrict__ ast,
                                                    float* __restrict__ adt) {
    int tid = blockIdx.x * 256 + threadIdx.x;
    if (tid >= N_NODES * HEADS) return;
    int h = tid / N_NODES;  // head-major: coalesced reads and writes
    int n = tid % N_NODES;
    const uint4* row4 = (const uint4*)(xpt + ((h * N_NODES + n) << 4));
    uint4 r0 = row4[0], r1 = row4[1];
    unsigned uu[8] = {r0.x, r0.y, r0.z, r0.w, r1.x, r1.y, r1.z, r1.w};
    float s = 0.f, d = 0.f;
#pragma unroll
    for (int q = 0; q < 8; q++) {
        float v0 = bf2f((unsigned short)(uu[q] & 0xffffu));
        float v1 = bf2f((unsigned short)(uu[q] >> 16));
        s += v0 * a_src[h * HID + 2 * q] + v1 * a_src[h * HID + 2 * q + 1];
        d += v0 * a_dst[h * HID + 2 * q] + v1 * a_dst[h * HID + 2 * q + 1];
    }
    ast[tid] = s;
    adt[tid] = d;
}

// ---- K3: CSR build (count / scan+deg-hist / scatter / deg-scatter) ----
__global__ void count_kernel(const int* __restrict__ ei, int* __restrict__ cnt) {
    int e = blockIdx.x * 256 + threadIdx.x;
    if (e < N_EDGES) atomicAdd(&cnt[ei[N_EDGES + e]], 1);
}

// Exclusive scan of degree counts -> offs/curs; also builds a 64-bin degree
// histogram and its exclusive scan -> dcur (cursors for counting-sort by degree).
__global__ __launch_bounds__(1024) void scan_kernel(const int* __restrict__ cnt,
                                                    int* __restrict__ offs,
                                                    int* __restrict__ curs,
                                                    int* __restrict__ dcur) {
    __shared__ int lds[1024];
    __shared__ int dh[64];
    const int tid = threadIdx.x;
    if (tid < 64) dh[tid] = 0;
    __syncthreads();
    const int base = tid * 10;
    int local[10];
    int s = 0;
#pragma unroll
    for (int i = 0; i < 10; i++) {
        int idx = base + i;
        int v = (idx < N_NODES) ? cnt[idx] : 0;
        if (idx < N_NODES) atomicAdd(&dh[v < 63 ? v : 63], 1);
        local[i] = s;
        s += v;
    }
    lds[tid] = s;
    __syncthreads();
    for (int off = 1; off < 1024; off <<= 1) {
        int v = (tid >= off) ? lds[tid - off] : 0;
        __syncthreads();
        lds[tid] += v;
        __syncthreads();
    }
    int excl = lds[tid] - s;
    for (int i = 0; i < 10; i++) {
        int idx = base + i;
        if (idx < N_NODES) {
            int o = excl + local[i];
            offs[idx] = o;
            curs[idx] = o;
        }
    }
    __syncthreads();
    if (tid == 0) {  // tiny serial exclusive scan of 64 bins
        int acc = 0;
#pragma unroll
        for (int b = 0; b < 64; b++) { int v = dh[b]; dcur[b] = acc; acc += v; }
    }
}

__global__ void scatter_kernel(const int* __restrict__ ei, int* __restrict__ curs,
                               int* __restrict__ ssrc) {
    int e = blockIdx.x * 256 + threadIdx.x;
    if (e < N_EDGES) {
        int d = ei[N_EDGES + e];
        int pos = atomicAdd(&curs[d], 1);
        ssrc[pos] = ei[e];
    }
}

// counting-sort nodes by degree: perm[sorted_pos] = node
__global__ void degscatter_kernel(const int* __restrict__ cnt, int* __restrict__ dcur,
                                  int* __restrict__ perm) {
    int n = blockIdx.x * 256 + threadIdx.x;
    if (n < N_NODES) {
        int d = cnt[n];
        d = d < 63 ? d : 63;
        int pos = atomicAdd(&dcur[d], 1);
        perm[pos] = n;
    }
}

// ---- K4: XCD-partitioned, degree-sorted, 2-heads-per-lane aggregation ----
// blockIdx.x & 7 -> intended XCD; group owns heads [g*50/8,(g+1)*50/8) (6-7).
// Wave w handles heads {hstart+2w, hstart+2w+1} in ONE edge pass: per edge
// 7 independent loads in flight (1 ssrc + 2 ast + 4 b128 xpt) -> high MLP.
// dst = perm[...]: wave-mates have near-equal degree -> no divergence tail.
__global__ __launch_bounds__(256) void agg_kernel(const unsigned short* __restrict__ xpt,
                                                  const float* __restrict__ ast,
                                                  const float* __restrict__ adt,
                                                  const int* __restrict__ offs,
                                                  const int* __restrict__ cnt,
                                                  const int* __restrict__ ssrc,
                                                  const int* __restrict__ perm,
                                                  float* __restrict__ hsum) {
    const int t = threadIdx.x;
    const int wave = t >> 6, lane = t & 63;
    const int grp = blockIdx.x & 7;  // intended XCD
    const int db = blockIdx.x >> 3;  // dst-block 0..156
    const int idx = db * 64 + lane;
    const int hstart = (grp * HEADS) >> 3;
    const int hend = ((grp + 1) * HEADS) >> 3;
    const bool dv = (idx < N_NODES);
    const int dst = dv ? perm[idx] : 0;
    int h0 = hstart + 2 * wave, h1 = h0 + 1;
    const bool v0 = (h0 < hend), v1 = (h1 < hend);
    if (!v0) h0 = hstart;  // clamp to a safe, L2-resident head
    if (!v1) h1 = hstart;
    float acc0[16], acc1[16];
#pragma unroll
    for (int c = 0; c < 16; c++) { acc0[c] = 0.f; acc1[c] = 0.f; }
    float den0 = 0.f, den1 = 0.f;
    if (dv) {
        const int start = offs[dst];
        const int deg = cnt[dst];
        const float adv0 = adt[h0 * N_NODES + dst];
        const float adv1 = adt[h1 * N_NODES + dst];
        const float* ash0 = ast + h0 * N_NODES;
        const float* ash1 = ast + h1 * N_NODES;
        const unsigned short* xph0 = xpt + ((size_t)(h0 * N_NODES) << 4);
        const unsigned short* xph1 = xpt + ((size_t)(h1 * N_NODES) << 4);
        int srcN = (0 < deg) ? ssrc[start] : dst;  // prefetch rotation
        for (int e = 0; e <= deg; e++) {           // e==deg -> self loop
            const int src = srcN;
            srcN = (e + 1 < deg) ? ssrc[start + e + 1] : dst;
            const float s0 = ash0[src], s1 = ash1[src];
            const uint4* p0 = (const uint4*)(xph0 + ((size_t)src << 4));
            const uint4* p1 = (const uint4*)(xph1 + ((size_t)src << 4));
            uint4 a = p0[0], b = p0[1], c = p1[0], d = p1[1];
            float l0 = s0 + adv0; l0 = (l0 > 0.f) ? l0 : 0.2f * l0;
            float l1 = s1 + adv1; l1 = (l1 > 0.f) ? l1 : 0.2f * l1;
            const float w0 = __expf(l0), w1 = __expf(l1);
            den0 += w0; den1 += w1;
            unsigned u0[8] = {a.x, a.y, a.z, a.w, b.x, b.y, b.z, b.w};
            unsigned u1[8] = {c.x, c.y, c.z, c.w, d.x, d.y, d.z, d.w};
#pragma unroll
            for (int q = 0; q < 8; q++) {
                acc0[2 * q + 0] += w0 * bf2f((unsigned short)(u0[q] & 0xffffu));
                acc0[2 * q + 1] += w0 * bf2f((unsigned short)(u0[q] >> 16));
                acc1[2 * q + 0] += w1 * bf2f((unsigned short)(u1[q] & 0xffffu));
                acc1[2 * q + 1] += w1 * bf2f((unsigned short)(u1[q] >> 16));
            }
        }
    }
    const float i0 = v0 ? (1.f / den0) : 0.f;  // den>0 when dv (self loop)
    const float i1 = v1 ? (1.f / den1) : 0.f;
    // reduce the block's 4 waves (disjoint heads, same dst per lane)
    __shared__ float red[64 * 17];
    for (int i = t; i < 64 * 17; i += 256) red[i] = 0.f;
    __syncthreads();
    if (dv) {
#pragma unroll
        for (int c = 0; c < 16; c++)
            atomicAdd(&red[lane * 17 + c], acc0[c] * i0 + acc1[c] * i1);
    }
    __syncthreads();
    {
        const int dl = t >> 2, c0 = (t & 3) * 4;
        const int i2 = db * 64 + dl;
        if (i2 < N_NODES) {
            const int d2 = perm[i2];
#pragma unroll
            for (int i = 0; i < 4; i++)
                atomicAdd(&hsum[(d2 << 4) + c0 + i], red[dl * 17 + c0 + i]);
        }
    }
}

// ---- K5: per-graph mean pool (+ head mean + bias) + FC. One block per graph. ----
__global__ __launch_bounds__(256) void pool_kernel(const float* __restrict__ hsum,
                                                   const int* __restrict__ batch,
                                                   const float* __restrict__ bias,
                                                   const float* __restrict__ fc_w,
                                                   const float* __restrict__ fc_b,
                                                   float* __restrict__ out) {
    const int g = blockIdx.x;
    const int t = threadIdx.x;
    int a = 0, b = N_NODES;
    while (a < b) { int m = (a + b) >> 1; if (batch[m] < g) a = m + 1; else b = m; }
    const int lo = a;
    b = N_NODES;
    while (a < b) { int m = (a + b) >> 1; if (batch[m] < g + 1) a = m + 1; else b = m; }
    const int hi = a;
    const int cntn = hi - lo;
    float acc[16];
#pragma unroll
    for (int c = 0; c < 16; c++) acc[c] = 0.f;
    for (int n = lo + t; n < hi; n += 256) {
        const float4* r = (const float4*)(hsum + (n << 4));
        float4 v0 = r[0], v1 = r[1], v2 = r[2], v3 = r[3];
        acc[0] += v0.x; acc[1] += v0.y; acc[2] += v0.z; acc[3] += v0.w;
        acc[4] += v1.x; acc[5] += v1.y; acc[6] += v1.z; acc[7] += v1.w;
        acc[8] += v2.x; acc[9] += v2.y; acc[10] += v2.z; acc[11] += v2.w;
        acc[12] += v3.x; acc[13] += v3.y; acc[14] += v3.z; acc[15] += v3.w;
    }
    __shared__ float red[256][17];
#pragma unroll
    for (int c = 0; c < 16; c++) red[t][c] = acc[c];
    __syncthreads();
    for (int s = 128; s > 0; s >>= 1) {
        if (t < s)
#pragma unroll
            for (int c = 0; c < 16; c++) red[t][c] += red[t + s][c];
        __syncthreads();
    }
    __shared__ float pooled[16];
    if (t < 16) {
        float v = 0.f;
        if (cntn > 0) v = red[0][t] / ((float)cntn * (float)HEADS) + bias[t];
        pooled[t] = v;
    }
    __syncthreads();
    if (t < OUT_DIM) {
        float s = fc_b[t];
#pragma unroll
        for (int c = 0; c < HID; c++) s += pooled[c] * fc_w[c * OUT_DIM + t];
        out[g * OUT_DIM + t] = s;
    }
}

// ---- workspace layout (bytes) ----
#define XPT_OFF 0             /* 50*10000*16*2 = 16,000,000 */
#define AST_OFF 16000000      /* 50*10000*4    =  2,000,000 */
#define ADT_OFF 18000000      /* 50*10000*4    =  2,000,000 */
#define SSRC_OFF 20000000     /* 160000*4      =    640,000 */
#define OFFS_OFF 20640000     /* 10000*4       =     40,000 */
#define CURS_OFF 20680000     /* 10000*4       =     40,000 */
#define CNT_OFF 20720000      /* 10000*4       =     40,000  (zeroed) */
#define HSUM_OFF 20760000     /* 10000*16*4    =    640,000  (zeroed) */
#define DCUR_OFF 21400000     /* 64*4          =        256 */
#define PERM_OFF 21400256     /* 10000*4       =     40,000 */

extern "C" void kernel_launch(void* const* d_in, const int* in_sizes, int n_in,
                              void* d_out, int out_size, void* d_ws, size_t ws_size,
                              hipStream_t stream) {
    const float* x = (const float*)d_in[0];
    const int* ei = (const int*)d_in[1];
    const int* batch = (const int*)d_in[2];
    const float* W = (const float*)d_in[4];
    const float* a_src = (const float*)d_in[5];
    const float* a_dst = (const float*)d_in[6];
    const float* bias = (const float*)d_in[7];
    const float* fc_w = (const float*)d_in[8];
    const float* fc_b = (const float*)d_in[9];
    float* out = (float*)d_out;

    char* ws = (char*)d_ws;
    unsigned short* xpt = (unsigned short*)(ws + XPT_OFF);
    float* ast = (float*)(ws + AST_OFF);
    float* adt = (float*)(ws + ADT_OFF);
    int* ssrc = (int*)(ws + SSRC_OFF);
    int* offs = (int*)(ws + OFFS_OFF);
    int* curs = (int*)(ws + CURS_OFF);
    int* cntc = (int*)(ws + CNT_OFF);
    float* hsum = (float*)(ws + HSUM_OFF);
    int* dcur = (int*)(ws + DCUR_OFF);
    int* perm = (int*)(ws + PERM_OFF);

    // zero degree counts + hsum (contiguous)
    hipMemsetAsync(ws + CNT_OFF, 0, 40000 + 640000, stream);

    gemm_kernel<<<dim3((NHID + 63) / 64, (N_NODES + 127) / 128), 256, 0, stream>>>(x, W, xpt);
    alpha_kernel<<<(N_NODES * HEADS + 255) / 256, 256, 0, stream>>>(xpt, a_src, a_dst, ast, adt);
    count_kernel<<<(N_EDGES + 255) / 256, 256, 0, stream>>>(ei, cntc);
    scan_kernel<<<1, 1024, 0, stream>>>(cntc, offs, curs, dcur);
    scatter_kernel<<<(N_EDGES + 255) / 256, 256, 0, stream>>>(ei, curs, ssrc);
    degscatter_kernel<<<(N_NODES + 255) / 256, 256, 0, stream>>>(cntc, dcur, perm);
    agg_kernel<<<8 * ((N_NODES + 63) / 64), 256, 0, stream>>>(xpt, ast, adt, offs, cntc, ssrc,
                                                              perm, hsum);
    pool_kernel<<<N_GRAPHS, 256, 0, stream>>>(hsum, batch, bias, fc_w, fc_b, out);
}

// Round 6
// 274.246 us; speedup vs baseline: 1.1173x; 1.1173x over previous
//
#include <hip/hip_runtime.h>

#define N_NODES 10000
#define N_EDGES 160000
#define IN_DIM 128
#define HID 16
#define HEADS 50
#define OUT_DIM 10
#define N_GRAPHS 8
#define NHID (HEADS * HID) /* 800 */

// 8 head-groups: grp g owns heads [hstart(g), hstart(g+1)), 6 or 7 heads.
// hstart(g) = floor(g*50/8) = (g*25)>>2  -> 0,6,12,18,25,31,37,43,50
static __device__ __forceinline__ int hstart_of(int g) { return (g * 25) >> 2; }

// ---- bf16 helpers (self-contained, RNE) ----
static __device__ __forceinline__ unsigned short f2bf(float f) {
    union { float f; unsigned u; } v; v.f = f;
    unsigned u = v.u;
    unsigned r = (u + 0x7fffu + ((u >> 16) & 1u)) >> 16;
    return (unsigned short)r;
}
static __device__ __forceinline__ float bits2f(unsigned u) {
    union { unsigned u; float f; } v; v.u = u;
    return v.f;
}
static __device__ __forceinline__ float bf2f(unsigned short s) {
    return bits2f(((unsigned)s) << 16);
}

// xpg element offset for (head h, node n, channel c), grp-packed layout:
// base = hstart(g)*N_NODES*16 ; off = base + (n*cnt_g + hl)*16 + c
static __device__ __forceinline__ size_t xpg_off(int h, int n, int c) {
    int g = (8 * h + 7) / 50;  // inverse of hstart
    int hs = hstart_of(g), he = hstart_of(g + 1);
    int cnt = he - hs, hl = h - hs;
    return (size_t)hs * N_NODES * 16 + ((size_t)n * cnt + hl) * 16 + c;
}
static __device__ __forceinline__ int astg_off(int h, int n) {
    int g = (8 * h + 7) / 50;
    int hs = hstart_of(g), he = hstart_of(g + 1);
    return hs * N_NODES + n * (he - hs) + (h - hs);
}

// ---- K1: xpg = (x(10000x128) @ W(128x800)) grp-packed, bf16 ----
__global__ __launch_bounds__(256) void gemm_kernel(const float* __restrict__ x,
                                                   const float* __restrict__ W,
                                                   unsigned short* __restrict__ xpg) {
    __shared__ float As[64][128];  // As[k][m]
    __shared__ float Bs[64][64];   // Bs[k][n]
    const int tid = threadIdx.x;
    const int m0 = blockIdx.y * 128;
    const int n0 = blockIdx.x * 64;
    const int tx = tid & 15, ty = tid >> 4;
    float acc[8][4] = {};
    const int am = tid & 127;         // A loader: m in tile
    const int akg = (tid >> 7) * 32;  // A loader: k group base (0 or 32)
    const int bn = (tid & 15) * 4;    // B loader: n in tile
    const int bk = tid >> 4;          // B loader: k row base

    for (int kk = 0; kk < IN_DIM; kk += 64) {
        const int gm = m0 + am;
#pragma unroll
        for (int i = 0; i < 8; i++) {
            int k4 = akg + i * 4;
            float4 v = make_float4(0.f, 0.f, 0.f, 0.f);
            if (gm < N_NODES) v = *(const float4*)(x + gm * IN_DIM + kk + k4);
            As[k4 + 0][am] = v.x; As[k4 + 1][am] = v.y;
            As[k4 + 2][am] = v.z; As[k4 + 3][am] = v.w;
        }
#pragma unroll
        for (int i = 0; i < 4; i++) {
            int k = bk + i * 16;
            float4 v = make_float4(0.f, 0.f, 0.f, 0.f);
            if (n0 + bn < NHID) v = *(const float4*)(W + (kk + k) * NHID + n0 + bn);
            *(float4*)&Bs[k][bn] = v;
        }
        __syncthreads();
#pragma unroll
        for (int k = 0; k < 64; k++) {
            float4 a0 = *(const float4*)&As[k][ty * 8];
            float4 a1 = *(const float4*)&As[k][ty * 8 + 4];
            float4 b = *(const float4*)&Bs[k][tx * 4];
            float av[8] = {a0.x, a0.y, a0.z, a0.w, a1.x, a1.y, a1.z, a1.w};
            float bv[4] = {b.x, b.y, b.z, b.w};
#pragma unroll
            for (int i = 0; i < 8; i++)
#pragma unroll
                for (int j = 0; j < 4; j++) acc[i][j] += av[i] * bv[j];
        }
        __syncthreads();
    }
    const int gn = n0 + tx * 4;     // 4-aligned -> single head per thread
    const int h = gn >> 4;
    const int c0 = gn & 15;
    if (gn < NHID) {
#pragma unroll
        for (int i = 0; i < 8; i++) {
            int gm = m0 + ty * 8 + i;
            if (gm < N_NODES) {
                ushort4 o;
                o.x = f2bf(acc[i][0]); o.y = f2bf(acc[i][1]);
                o.z = f2bf(acc[i][2]); o.w = f2bf(acc[i][3]);
                *(ushort4*)(xpg + xpg_off(h, gm, c0)) = o;  // 8B aligned
            }
        }
    }
}

// ---- K2: astg/adtg (grp-packed) from xpg ----
__global__ __launch_bounds__(256) void alpha_kernel(const unsigned short* __restrict__ xpg,
                                                    const float* __restrict__ a_src,
                                                    const float* __restrict__ a_dst,
                                                    float* __restrict__ astg,
                                                    float* __restrict__ adtg) {
    int tid = blockIdx.x * 256 + threadIdx.x;
    if (tid >= N_NODES * HEADS) return;
    int h = tid / N_NODES;
    int n = tid % N_NODES;
    const uint4* row4 = (const uint4*)(xpg + xpg_off(h, n, 0));  // 32B aligned
    uint4 r0 = row4[0], r1 = row4[1];
    unsigned uu[8] = {r0.x, r0.y, r0.z, r0.w, r1.x, r1.y, r1.z, r1.w};
    float s = 0.f, d = 0.f;
#pragma unroll
    for (int q = 0; q < 8; q++) {
        float v0 = bf2f((unsigned short)(uu[q] & 0xffffu));
        float v1 = bf2f((unsigned short)(uu[q] >> 16));
        s += v0 * a_src[h * HID + 2 * q] + v1 * a_src[h * HID + 2 * q + 1];
        d += v0 * a_dst[h * HID + 2 * q] + v1 * a_dst[h * HID + 2 * q + 1];
    }
    int o = astg_off(h, n);
    astg[o] = s;
    adtg[o] = d;
}

// ---- K3: CSR build (count / scan+deg-hist / scatter / deg-scatter) ----
__global__ void count_kernel(const int* __restrict__ ei, int* __restrict__ cnt) {
    int e = blockIdx.x * 256 + threadIdx.x;
    if (e < N_EDGES) atomicAdd(&cnt[ei[N_EDGES + e]], 1);
}

// Exclusive scan of degrees -> offs/curs; 64-bin DESCENDING-degree histogram
// scan -> dcur (so perm lists high-degree nodes first: long waves launch first).
__global__ __launch_bounds__(1024) void scan_kernel(const int* __restrict__ cnt,
                                                    int* __restrict__ offs,
                                                    int* __restrict__ curs,
                                                    int* __restrict__ dcur) {
    __shared__ int lds[1024];
    __shared__ int dh[64];
    const int tid = threadIdx.x;
    if (tid < 64) dh[tid] = 0;
    __syncthreads();
    const int base = tid * 10;
    int local[10];
    int s = 0;
#pragma unroll
    for (int i = 0; i < 10; i++) {
        int idx = base + i;
        int v = (idx < N_NODES) ? cnt[idx] : 0;
        if (idx < N_NODES) atomicAdd(&dh[63 - (v < 63 ? v : 63)], 1);
        local[i] = s;
        s += v;
    }
    lds[tid] = s;
    __syncthreads();
    for (int off = 1; off < 1024; off <<= 1) {
        int v = (tid >= off) ? lds[tid - off] : 0;
        __syncthreads();
        lds[tid] += v;
        __syncthreads();
    }
    int excl = lds[tid] - s;
    for (int i = 0; i < 10; i++) {
        int idx = base + i;
        if (idx < N_NODES) {
            int o = excl + local[i];
            offs[idx] = o;
            curs[idx] = o;
        }
    }
    __syncthreads();
    if (tid == 0) {
        int acc = 0;
#pragma unroll
        for (int b = 0; b < 64; b++) { int v = dh[b]; dcur[b] = acc; acc += v; }
    }
}

__global__ void scatter_kernel(const int* __restrict__ ei, int* __restrict__ curs,
                               int* __restrict__ ssrc) {
    int e = blockIdx.x * 256 + threadIdx.x;
    if (e < N_EDGES) {
        int d = ei[N_EDGES + e];
        int pos = atomicAdd(&curs[d], 1);
        ssrc[pos] = ei[e];
    }
}

__global__ void degscatter_kernel(const int* __restrict__ cnt, int* __restrict__ dcur,
                                  int* __restrict__ perm) {
    int n = blockIdx.x * 256 + threadIdx.x;
    if (n < N_NODES) {
        int d = cnt[n];
        d = d < 63 ? d : 63;
        int pos = atomicAdd(&dcur[63 - d], 1);  // descending degree
        perm[pos] = n;
    }
}

// ---- K4: coalesced, barrier-free aggregation ----
// grid 20000 = 8 grps x 2500; blockIdx&7 -> grp (XCD round-robin: grp slice
// ~2.2MB stays L2-resident). Block = 4 waves; wave w owns dst = perm[db*4+w].
// Lane l covers channels {2l, 2l+1} of the grp's packed 96-112 channels
// (head hl = l>>3). Per edge: 1 scalar ssrc load + ~4 coalesced line
// transactions for the xp slice + broadcast ast loads. No __syncthreads.
__global__ __launch_bounds__(256) void agg_kernel(const unsigned short* __restrict__ xpg,
                                                  const float* __restrict__ astg,
                                                  const float* __restrict__ adtg,
                                                  const int* __restrict__ offs,
                                                  const int* __restrict__ cnt,
                                                  const int* __restrict__ ssrc,
                                                  const int* __restrict__ perm,
                                                  float* __restrict__ hsum) {
    const int t = threadIdx.x;
    const int wave = t >> 6, lane = t & 63;
    const int g = blockIdx.x & 7;
    const int db = blockIdx.x >> 3;  // 0..2499
    const int hs = hstart_of(g), he = hstart_of(g + 1);
    const int cg = he - hs;                       // 6 or 7 heads
    const int hl = lane >> 3;                     // local head
    const int c2 = (lane & 7) * 2;                // channel pair base
    const int dst_idx = db * 4 + wave;            // 0..9999
    int dst = perm[dst_idx];
    dst = __builtin_amdgcn_readfirstlane(dst);
    const int start = __builtin_amdgcn_readfirstlane(offs[dst]);
    const int deg = __builtin_amdgcn_readfirstlane(cnt[dst]);
    const float* astg_g = astg + hs * N_NODES;
    const float* adtg_g = adtg + hs * N_NODES;
    const unsigned short* xpg_g = xpg + (size_t)hs * N_NODES * 16;

    float acc0 = 0.f, acc1 = 0.f, den = 0.f;
    const bool active = (lane < cg * 8);
    if (active) {
        const float adv = adtg_g[dst * cg + hl];
        for (int e = 0; e <= deg; e++) {  // e==deg -> self loop
            const int src = (e < deg) ? ssrc[start + e] : dst;
            const float a = astg_g[src * cg + hl];
            const unsigned px = *(const unsigned*)(xpg_g + ((size_t)src * cg + hl) * 16 + c2);
            float l = a + adv;
            l = (l > 0.f) ? l : 0.2f * l;  // leaky relu
            const float w = __expf(l);     // no max-shift: logits bounded
            den += w;
            acc0 += w * bits2f(px << 16);
            acc1 += w * bits2f(px & 0xffff0000u);
        }
    }
    const float inv = active ? (1.f / den) : 0.f;  // den>0: self loop
    float v0 = acc0 * inv, v1 = acc1 * inv;
    // sum over heads: lanes {c2base, +8, +16, ...} -> butterfly over bits 3..5
    v0 += __shfl_xor(v0, 8);  v1 += __shfl_xor(v1, 8);
    v0 += __shfl_xor(v0, 16); v1 += __shfl_xor(v1, 16);
    v0 += __shfl_xor(v0, 32); v1 += __shfl_xor(v1, 32);
    if (lane < 8) {
        atomicAdd(&hsum[(dst << 4) + 2 * lane + 0], v0);
        atomicAdd(&hsum[(dst << 4) + 2 * lane + 1], v1);
    }
}

// ---- K5: per-graph mean pool (+ head mean + bias) + FC. One block per graph. ----
__global__ __launch_bounds__(256) void pool_kernel(const float* __restrict__ hsum,
                                                   const int* __restrict__ batch,
                                                   const float* __restrict__ bias,
                                                   const float* __restrict__ fc_w,
                                                   const float* __restrict__ fc_b,
                                                   float* __restrict__ out) {
    const int g = blockIdx.x;
    const int t = threadIdx.x;
    int a = 0, b = N_NODES;
    while (a < b) { int m = (a + b) >> 1; if (batch[m] < g) a = m + 1; else b = m; }
    const int lo = a;
    b = N_NODES;
    while (a < b) { int m = (a + b) >> 1; if (batch[m] < g + 1) a = m + 1; else b = m; }
    const int hi = a;
    const int cntn = hi - lo;
    float acc[16];
#pragma unroll
    for (int c = 0; c < 16; c++) acc[c] = 0.f;
    for (int n = lo + t; n < hi; n += 256) {
        const float4* r = (const float4*)(hsum + (n << 4));
        float4 v0 = r[0], v1 = r[1], v2 = r[2], v3 = r[3];
        acc[0] += v0.x; acc[1] += v0.y; acc[2] += v0.z; acc[3] += v0.w;
        acc[4] += v1.x; acc[5] += v1.y; acc[6] += v1.z; acc[7] += v1.w;
        acc[8] += v2.x; acc[9] += v2.y; acc[10] += v2.z; acc[11] += v2.w;
        acc[12] += v3.x; acc[13] += v3.y; acc[14] += v3.z; acc[15] += v3.w;
    }
    __shared__ float red[256][17];
#pragma unroll
    for (int c = 0; c < 16; c++) red[t][c] = acc[c];
    __syncthreads();
    for (int s = 128; s > 0; s >>= 1) {
        if (t < s)
#pragma unroll
            for (int c = 0; c < 16; c++) red[t][c] += red[t + s][c];
        __syncthreads();
    }
    __shared__ float pooled[16];
    if (t < 16) {
        float v = 0.f;
        if (cntn > 0) v = red[0][t] / ((float)cntn * (float)HEADS) + bias[t];
        pooled[t] = v;
    }
    __syncthreads();
    if (t < OUT_DIM) {
        float s = fc_b[t];
#pragma unroll
        for (int c = 0; c < HID; c++) s += pooled[c] * fc_w[c * OUT_DIM + t];
        out[g * OUT_DIM + t] = s;
    }
}

// ---- workspace layout (bytes) ----
#define XPG_OFF 0             /* 50*10000*16*2 = 16,000,000 */
#define AST_OFF 16000000      /* 50*10000*4    =  2,000,000 */
#define ADT_OFF 18000000      /* 50*10000*4    =  2,000,000 */
#define SSRC_OFF 20000000     /* 160000*4      =    640,000 */
#define OFFS_OFF 20640000     /* 10000*4       =     40,000 */
#define CURS_OFF 20680000     /* 10000*4       =     40,000 */
#define CNT_OFF 20720000      /* 10000*4       =     40,000  (zeroed) */
#define HSUM_OFF 20760000     /* 10000*16*4    =    640,000  (zeroed) */
#define DCUR_OFF 21400000     /* 64*4          =        256 */
#define PERM_OFF 21400256     /* 10000*4       =     40,000 */

extern "C" void kernel_launch(void* const* d_in, const int* in_sizes, int n_in,
                              void* d_out, int out_size, void* d_ws, size_t ws_size,
                              hipStream_t stream) {
    const float* x = (const float*)d_in[0];
    const int* ei = (const int*)d_in[1];
    const int* batch = (const int*)d_in[2];
    const float* W = (const float*)d_in[4];
    const float* a_src = (const float*)d_in[5];
    const float* a_dst = (const float*)d_in[6];
    const float* bias = (const float*)d_in[7];
    const float* fc_w = (const float*)d_in[8];
    const float* fc_b = (const float*)d_in[9];
    float* out = (float*)d_out;

    char* ws = (char*)d_ws;
    unsigned short* xpg = (unsigned short*)(ws + XPG_OFF);
    float* astg = (float*)(ws + AST_OFF);
    float* adtg = (float*)(ws + ADT_OFF);
    int* ssrc = (int*)(ws + SSRC_OFF);
    int* offs = (int*)(ws + OFFS_OFF);
    int* curs = (int*)(ws + CURS_OFF);
    int* cntc = (int*)(ws + CNT_OFF);
    float* hsum = (float*)(ws + HSUM_OFF);
    int* dcur = (int*)(ws + DCUR_OFF);
    int* perm = (int*)(ws + PERM_OFF);

    // zero degree counts + hsum (contiguous)
    hipMemsetAsync(ws + CNT_OFF, 0, 40000 + 640000, stream);

    gemm_kernel<<<dim3((NHID + 63) / 64, (N_NODES + 127) / 128), 256, 0, stream>>>(x, W, xpg);
    alpha_kernel<<<(N_NODES * HEADS + 255) / 256, 256, 0, stream>>>(xpg, a_src, a_dst, astg, adtg);
    count_kernel<<<(N_EDGES + 255) / 256, 256, 0, stream>>>(ei, cntc);
    scan_kernel<<<1, 1024, 0, stream>>>(cntc, offs, curs, dcur);
    scatter_kernel<<<(N_EDGES + 255) / 256, 256, 0, stream>>>(ei, curs, ssrc);
    degscatter_kernel<<<(N_NODES + 255) / 256, 256, 0, stream>>>(cntc, dcur, perm);
    agg_kernel<<<8 * (N_NODES / 4), 256, 0, stream>>>(xpg, astg, adtg, offs, cntc, ssrc,
                                                      perm, hsum);
    pool_kernel<<<N_GRAPHS, 256, 0, stream>>>(hsum, batch, bias, fc_w, fc_b, out);
}

// Round 7
// 237.672 us; speedup vs baseline: 1.2892x; 1.1539x over previous
//
#include <hip/hip_runtime.h>

#define N_NODES 10000
#define N_EDGES 160000
#define IN_DIM 128
#define HID 16
#define HEADS 50
#define OUT_DIM 10
#define N_GRAPHS 8
#define NHID (HEADS * HID) /* 800 */

// 8 head-groups: grp g owns heads [hstart(g), hstart(g+1)), 6 or 7 heads.
// hstart(g) = floor(g*50/8) -> 0,6,12,18,25,31,37,43,50
static __device__ __forceinline__ int hstart_of(int g) { return (g * 25) >> 2; }

typedef __attribute__((ext_vector_type(8))) short bfrag;   // 8 bf16 (4 VGPRs)
typedef __attribute__((ext_vector_type(4))) float ffrag;   // 4 fp32 acc

// ---- bf16 helpers (self-contained, RNE) ----
static __device__ __forceinline__ unsigned short f2bf(float f) {
    union { float f; unsigned u; } v; v.f = f;
    unsigned u = v.u;
    unsigned r = (u + 0x7fffu + ((u >> 16) & 1u)) >> 16;
    return (unsigned short)r;
}
static __device__ __forceinline__ float bits2f(unsigned u) {
    union { unsigned u; float f; } v; v.u = u;
    return v.f;
}

// ---- K0a: x (fp32) -> xbf (bf16), vectorized ----
__global__ __launch_bounds__(256) void xcast_kernel(const float* __restrict__ x,
                                                    unsigned short* __restrict__ xbf) {
    int t = blockIdx.x * 256 + threadIdx.x;  // 320000 threads, 4 elems each
    if (t < N_NODES * IN_DIM / 4) {
        float4 v = ((const float4*)x)[t];
        ushort4 o;
        o.x = f2bf(v.x); o.y = f2bf(v.y); o.z = f2bf(v.z); o.w = f2bf(v.w);
        ((ushort4*)xbf)[t] = o;
    }
}

// ---- K0b: W[k][n] (fp32) -> wt[n][k] (bf16), write-coalesced ----
__global__ __launch_bounds__(256) void wcast_kernel(const float* __restrict__ W,
                                                    unsigned short* __restrict__ wt) {
    int t = blockIdx.x * 256 + threadIdx.x;  // 102400
    if (t < NHID * IN_DIM) {
        int n = t >> 7, k = t & 127;
        wt[t] = f2bf(W[k * NHID + n]);
    }
}

// ---- K1: MFMA bf16 GEMM, LDS-free, alpha fused into epilogue ----
// grid (10, 79), block 256 = 4 waves. Wave: 32 rows x 80 cols = 2x5 MFMA tiles.
// Each 16-col tile == one head's 16 channels -> epilogue writes grp-packed
// xpg8[g][n][8][16] bf16 and shfl-reduced ast/adt (fused alpha).
__global__ __launch_bounds__(256) void gemm_mfma(const unsigned short* __restrict__ xbf,
                                                 const unsigned short* __restrict__ wt,
                                                 const float* __restrict__ a_src,
                                                 const float* __restrict__ a_dst,
                                                 unsigned short* __restrict__ xpg,
                                                 float* __restrict__ astp,
                                                 float* __restrict__ adtp) {
    const int tid = threadIdx.x;
    const int wave = tid >> 6, lane = tid & 63;
    const int q = lane >> 4, r = lane & 15;
    const int m0 = blockIdx.y * 128 + wave * 32;  // wave rows m0..m0+31
    const int h0 = blockIdx.x * 5;                // 5 heads per block
    ffrag zf = {0.f, 0.f, 0.f, 0.f};
    ffrag acc[2][5];
#pragma unroll
    for (int mt = 0; mt < 2; mt++)
#pragma unroll
        for (int nt = 0; nt < 5; nt++) acc[mt][nt] = zf;

    // reads may overrun past node 9999 (guarded at store); xbf is followed by
    // wt in the workspace so reads stay inside the allocation.
#pragma unroll
    for (int kc = 0; kc < IN_DIM; kc += 32) {
        bfrag a[2], b[5];
#pragma unroll
        for (int mt = 0; mt < 2; mt++)
            a[mt] = *(const bfrag*)(xbf + (m0 + mt * 16 + r) * IN_DIM + kc + q * 8);
#pragma unroll
        for (int nt = 0; nt < 5; nt++)
            b[nt] = *(const bfrag*)(wt + ((h0 + nt) * 16 + r) * IN_DIM + kc + q * 8);
#pragma unroll
        for (int mt = 0; mt < 2; mt++)
#pragma unroll
            for (int nt = 0; nt < 5; nt++)
                acc[mt][nt] = __builtin_amdgcn_mfma_f32_16x16x32_bf16(a[mt], b[nt],
                                                                      acc[mt][nt], 0, 0, 0);
    }
#pragma unroll
    for (int nt = 0; nt < 5; nt++) {
        const int h = h0 + nt;
        const int g = (8 * h + 7) / 50;           // grp of head h
        const int hl = h - hstart_of(g);          // local head slot
        const float asw = a_src[h * HID + r];
        const float adw = a_dst[h * HID + r];
        unsigned short* xg = xpg + (size_t)g * (N_NODES * 128);
        float* ag = astp + g * (N_NODES * 8);
        float* dg = adtp + g * (N_NODES * 8);
#pragma unroll
        for (int mt = 0; mt < 2; mt++) {
            ffrag d = acc[mt][nt];  // rows m = m0+mt*16+q*4+i, col r
            float s[4], w[4];
#pragma unroll
            for (int i = 0; i < 4; i++) { s[i] = d[i] * asw; w[i] = d[i] * adw; }
#pragma unroll
            for (int off = 1; off < 16; off <<= 1) {
#pragma unroll
                for (int i = 0; i < 4; i++) {
                    s[i] += __shfl_xor(s[i], off);
                    w[i] += __shfl_xor(w[i], off);
                }
            }
#pragma unroll
            for (int i = 0; i < 4; i++) {
                const int node = m0 + mt * 16 + q * 4 + i;
                if (node < N_NODES) {
                    xg[node * 128 + hl * 16 + r] = f2bf(d[i]);
                    if (r == 0) {
                        ag[(node << 3) + hl] = s[i];
                        dg[(node << 3) + hl] = w[i];
                    }
                }
            }
        }
    }
}

// ---- K3: CSR build (count / scan+deg-hist / scatter / deg-scatter) ----
__global__ void count_kernel(const int* __restrict__ ei, int* __restrict__ cnt) {
    int e = blockIdx.x * 256 + threadIdx.x;
    if (e < N_EDGES) atomicAdd(&cnt[ei[N_EDGES + e]], 1);
}

__global__ __launch_bounds__(1024) void scan_kernel(const int* __restrict__ cnt,
                                                    int* __restrict__ offs,
                                                    int* __restrict__ curs,
                                                    int* __restrict__ dcur) {
    __shared__ int lds[1024];
    __shared__ int dh[64];
    const int tid = threadIdx.x;
    if (tid < 64) dh[tid] = 0;
    __syncthreads();
    const int base = tid * 10;
    int local[10];
    int s = 0;
#pragma unroll
    for (int i = 0; i < 10; i++) {
        int idx = base + i;
        int v = (idx < N_NODES) ? cnt[idx] : 0;
        if (idx < N_NODES) atomicAdd(&dh[63 - (v < 63 ? v : 63)], 1);
        local[i] = s;
        s += v;
    }
    lds[tid] = s;
    __syncthreads();
    for (int off = 1; off < 1024; off <<= 1) {
        int v = (tid >= off) ? lds[tid - off] : 0;
        __syncthreads();
        lds[tid] += v;
        __syncthreads();
    }
    int excl = lds[tid] - s;
    for (int i = 0; i < 10; i++) {
        int idx = base + i;
        if (idx < N_NODES) {
            int o = excl + local[i];
            offs[idx] = o;
            curs[idx] = o;
        }
    }
    __syncthreads();
    if (tid == 0) {
        int acc = 0;
#pragma unroll
        for (int b = 0; b < 64; b++) { int v = dh[b]; dcur[b] = acc; acc += v; }
    }
}

__global__ void scatter_kernel(const int* __restrict__ ei, int* __restrict__ curs,
                               int* __restrict__ ssrc) {
    int e = blockIdx.x * 256 + threadIdx.x;
    if (e < N_EDGES) {
        int d = ei[N_EDGES + e];
        int pos = atomicAdd(&curs[d], 1);
        ssrc[pos] = ei[e];
    }
}

__global__ void degscatter_kernel(const int* __restrict__ cnt, int* __restrict__ dcur,
                                  int* __restrict__ perm) {
    int n = blockIdx.x * 256 + threadIdx.x;
    if (n < N_NODES) {
        int d = cnt[n];
        d = d < 63 ? d : 63;
        int pos = atomicAdd(&dcur[63 - d], 1);  // descending degree
        perm[pos] = n;
    }
}

// ---- K4: coalesced, barrier-free aggregation (padded shift addressing) ----
// grid 20000 = 8 grps x 2500; blockIdx&7 -> grp (XCD round-robin; ~2.6MB slice
// L2-resident). Wave owns dst = perm[db*4+wave]; lane = (head hl = l>>3,
// channel pair c2 = (l&7)*2). Edge loop unrolled x2 for MLP. No barriers.
__global__ __launch_bounds__(256) void agg_kernel(const unsigned short* __restrict__ xpg,
                                                  const float* __restrict__ astp,
                                                  const float* __restrict__ adtp,
                                                  const int* __restrict__ offs,
                                                  const int* __restrict__ cnt,
                                                  const int* __restrict__ ssrc,
                                                  const int* __restrict__ perm,
                                                  float* __restrict__ hsum) {
    const int t = threadIdx.x;
    const int wave = t >> 6, lane = t & 63;
    const int g = blockIdx.x & 7;
    const int db = blockIdx.x >> 3;  // 0..2499
    const int cg = hstart_of(g + 1) - hstart_of(g);  // 6 or 7
    const int hl = lane >> 3;
    const int hl16c2 = ((lane >> 3) << 4) + (lane & 7) * 2;
    int dst = perm[db * 4 + wave];
    dst = __builtin_amdgcn_readfirstlane(dst);
    const int start = __builtin_amdgcn_readfirstlane(offs[dst]);
    const int deg = __builtin_amdgcn_readfirstlane(cnt[dst]);
    const float* ag = astp + g * (N_NODES * 8);
    const unsigned short* xg = xpg + (size_t)g * (N_NODES * 128);
    float acc0 = 0.f, acc1 = 0.f, den = 0.f;
    const bool active = (hl < cg);
    if (active) {
        const float adv = adtp[g * (N_NODES * 8) + (dst << 3) + hl];
        int e = 0;
        for (; e + 1 < deg; e += 2) {
            const int s0 = ssrc[start + e];
            const int s1 = ssrc[start + e + 1];
            const float a0 = ag[(s0 << 3) + hl];
            const float a1 = ag[(s1 << 3) + hl];
            const unsigned p0 = *(const unsigned*)(xg + (s0 << 7) + hl16c2);
            const unsigned p1 = *(const unsigned*)(xg + (s1 << 7) + hl16c2);
            float l0 = a0 + adv; l0 = fmaxf(l0, 0.2f * l0);
            float l1 = a1 + adv; l1 = fmaxf(l1, 0.2f * l1);
            const float w0 = __expf(l0), w1 = __expf(l1);
            den += w0 + w1;
            acc0 += w0 * bits2f(p0 << 16) + w1 * bits2f(p1 << 16);
            acc1 += w0 * bits2f(p0 & 0xffff0000u) + w1 * bits2f(p1 & 0xffff0000u);
        }
        for (; e <= deg; e++) {  // tail + self loop
            const int s0 = (e < deg) ? ssrc[start + e] : dst;
            const float a0 = ag[(s0 << 3) + hl];
            const unsigned p0 = *(const unsigned*)(xg + (s0 << 7) + hl16c2);
            float l0 = a0 + adv; l0 = fmaxf(l0, 0.2f * l0);
            const float w0 = __expf(l0);
            den += w0;
            acc0 += w0 * bits2f(p0 << 16);
            acc1 += w0 * bits2f(p0 & 0xffff0000u);
        }
    }
    const float inv = active ? (1.f / den) : 0.f;  // den>0: self loop
    float v0 = acc0 * inv, v1 = acc1 * inv;
    v0 += __shfl_xor(v0, 8);  v1 += __shfl_xor(v1, 8);
    v0 += __shfl_xor(v0, 16); v1 += __shfl_xor(v1, 16);
    v0 += __shfl_xor(v0, 32); v1 += __shfl_xor(v1, 32);
    if (lane < 8) {
        atomicAdd(&hsum[(dst << 4) + 2 * lane + 0], v0);
        atomicAdd(&hsum[(dst << 4) + 2 * lane + 1], v1);
    }
}

// ---- K5: per-graph mean pool (+ head mean + bias) + FC. One block per graph. ----
__global__ __launch_bounds__(256) void pool_kernel(const float* __restrict__ hsum,
                                                   const int* __restrict__ batch,
                                                   const float* __restrict__ bias,
                                                   const float* __restrict__ fc_w,
                                                   const float* __restrict__ fc_b,
                                                   float* __restrict__ out) {
    const int g = blockIdx.x;
    const int t = threadIdx.x;
    int a = 0, b = N_NODES;
    while (a < b) { int m = (a + b) >> 1; if (batch[m] < g) a = m + 1; else b = m; }
    const int lo = a;
    b = N_NODES;
    while (a < b) { int m = (a + b) >> 1; if (batch[m] < g + 1) a = m + 1; else b = m; }
    const int hi = a;
    const int cntn = hi - lo;
    float acc[16];
#pragma unroll
    for (int c = 0; c < 16; c++) acc[c] = 0.f;
    for (int n = lo + t; n < hi; n += 256) {
        const float4* r = (const float4*)(hsum + (n << 4));
        float4 v0 = r[0], v1 = r[1], v2 = r[2], v3 = r[3];
        acc[0] += v0.x; acc[1] += v0.y; acc[2] += v0.z; acc[3] += v0.w;
        acc[4] += v1.x; acc[5] += v1.y; acc[6] += v1.z; acc[7] += v1.w;
        acc[8] += v2.x; acc[9] += v2.y; acc[10] += v2.z; acc[11] += v2.w;
        acc[12] += v3.x; acc[13] += v3.y; acc[14] += v3.z; acc[15] += v3.w;
    }
    __shared__ float red[256][17];
#pragma unroll
    for (int c = 0; c < 16; c++) red[t][c] = acc[c];
    __syncthreads();
    for (int s = 128; s > 0; s >>= 1) {
        if (t < s)
#pragma unroll
            for (int c = 0; c < 16; c++) red[t][c] += red[t + s][c];
        __syncthreads();
    }
    __shared__ float pooled[16];
    if (t < 16) {
        float v = 0.f;
        if (cntn > 0) v = red[0][t] / ((float)cntn * (float)HEADS) + bias[t];
        pooled[t] = v;
    }
    __syncthreads();
    if (t < OUT_DIM) {
        float s = fc_b[t];
#pragma unroll
        for (int c = 0; c < HID; c++) s += pooled[c] * fc_w[c * OUT_DIM + t];
        out[g * OUT_DIM + t] = s;
    }
}

// ---- workspace layout (bytes) ----
#define XPG_OFF 0              /* 8*10000*8*16*2 = 20,480,000 */
#define ASTP_OFF 20480000      /* 8*10000*8*4    =  2,560,000 */
#define ADTP_OFF 23040000      /* 8*10000*8*4    =  2,560,000 */
#define XBF_OFF 25600000       /* 10000*128*2    =  2,560,000 (wt follows: OOB-read safe) */
#define WT_OFF 28160000        /* 800*128*2      =    204,800 */
#define SSRC_OFF 28364800      /* 160000*4       =    640,000 */
#define OFFS_OFF 29004800      /* 10000*4        =     40,000 */
#define CURS_OFF 29044800      /* 10000*4        =     40,000 */
#define CNT_OFF 29084800       /* 10000*4        =     40,000  (zeroed) */
#define HSUM_OFF 29124800      /* 10000*16*4     =    640,000  (zeroed) */
#define DCUR_OFF 29764800      /* 64*4           =        256 */
#define PERM_OFF 29765056      /* 10000*4        =     40,000 */

extern "C" void kernel_launch(void* const* d_in, const int* in_sizes, int n_in,
                              void* d_out, int out_size, void* d_ws, size_t ws_size,
                              hipStream_t stream) {
    const float* x = (const float*)d_in[0];
    const int* ei = (const int*)d_in[1];
    const int* batch = (const int*)d_in[2];
    const float* W = (const float*)d_in[4];
    const float* a_src = (const float*)d_in[5];
    const float* a_dst = (const float*)d_in[6];
    const float* bias = (const float*)d_in[7];
    const float* fc_w = (const float*)d_in[8];
    const float* fc_b = (const float*)d_in[9];
    float* out = (float*)d_out;

    char* ws = (char*)d_ws;
    unsigned short* xpg = (unsigned short*)(ws + XPG_OFF);
    float* astp = (float*)(ws + ASTP_OFF);
    float* adtp = (float*)(ws + ADTP_OFF);
    unsigned short* xbf = (unsigned short*)(ws + XBF_OFF);
    unsigned short* wt = (unsigned short*)(ws + WT_OFF);
    int* ssrc = (int*)(ws + SSRC_OFF);
    int* offs = (int*)(ws + OFFS_OFF);
    int* curs = (int*)(ws + CURS_OFF);
    int* cntc = (int*)(ws + CNT_OFF);
    float* hsum = (float*)(ws + HSUM_OFF);
    int* dcur = (int*)(ws + DCUR_OFF);
    int* perm = (int*)(ws + PERM_OFF);

    // zero degree counts + hsum (contiguous)
    hipMemsetAsync(ws + CNT_OFF, 0, 40000 + 640000, stream);

    xcast_kernel<<<(N_NODES * IN_DIM / 4 + 255) / 256, 256, 0, stream>>>(x, xbf);
    wcast_kernel<<<(NHID * IN_DIM + 255) / 256, 256, 0, stream>>>(W, wt);
    gemm_mfma<<<dim3(NHID / 80, (N_NODES + 127) / 128), 256, 0, stream>>>(
        xbf, wt, a_src, a_dst, xpg, astp, adtp);
    count_kernel<<<(N_EDGES + 255) / 256, 256, 0, stream>>>(ei, cntc);
    scan_kernel<<<1, 1024, 0, stream>>>(cntc, offs, curs, dcur);
    scatter_kernel<<<(N_EDGES + 255) / 256, 256, 0, stream>>>(ei, curs, ssrc);
    degscatter_kernel<<<(N_NODES + 255) / 256, 256, 0, stream>>>(cntc, dcur, perm);
    agg_kernel<<<8 * (N_NODES / 4), 256, 0, stream>>>(xpg, astp, adtp, offs, cntc, ssrc,
                                                      perm, hsum);
    pool_kernel<<<N_GRAPHS, 256, 0, stream>>>(hsum, batch, bias, fc_w, fc_b, out);
}